// Round 9
// baseline (31.910 us; speedup 1.0000x reference)
//
#include <hip/hip_runtime.h>

// TransE 'rhs': pred[b,n] = MARGIN - ||(s+r)[b] - e[n]||_2. B=32,N=200k,D=64 fp32.
//
// R8 post-mortem: halving compute moved 29.1->27.9us only -> not path-bound.
// All 8 rounds pin at ~2.7TB/s effective; fast references (fillBuffer 6.9TB/s,
// m13 copy 6.3TB/s) use plain per-lane coalesced loads. Hypothesis: the
// global_load_lds DMA queue per CU is shallow (~16 outstanding) -> ~3TB/s cap
// when fed from HBM. R9: identical math/pipeline to R8, but e is delivered by
// plain coalesced global_load_dwordx4 into registers (both tiles prefetched,
// 16 loads in flight), then transposed to fragment layout via one LDS
// write/read bounce (swizzled, R8's layout). LDS 16KB/block, 3125 one-wave
// blocks -> ~12 waves/CU (was 5).

#define MARGIN 9.0f

typedef __attribute__((ext_vector_type(8)))  short bf16x8;
typedef __attribute__((ext_vector_type(16))) float f32x16;

__device__ __forceinline__ unsigned swz(unsigned p) {   // fragment byte addr
    return p ^ (((p >> 8) & 7u) << 4);                  // involution, in-row
}
__device__ __forceinline__ void lgkm0_fence() {         // cross-lane LDS fence
    asm volatile("s_waitcnt lgkmcnt(0)" ::: "memory");
    __builtin_amdgcn_sched_barrier(0);
}

__global__ __launch_bounds__(64)
void transe9(const float* __restrict__ s_emb,
             const float* __restrict__ rel_emb,
             const float* __restrict__ emb_e,
             float* __restrict__ out, int N)
{
    __shared__ char eT[8192];    // e-tile in fragment layout (reused t0,t1)
    __shared__ char oq[8192];    // q staging, then out staging [32][64] f32
    const int lane = threadIdx.x & 63;
    const int m = lane & 31, h = lane >> 5;

    // ---- 1. q global loads first (oldest in vmcnt queue) ----
    const float4* s4 = (const float4*)s_emb;
    const float4* r4 = (const float4*)rel_emb;
    float4 sreg[8], rreg[8];
#pragma unroll
    for (int k = 0; k < 8; ++k) sreg[k] = s4[k*64 + lane];
#pragma unroll
    for (int k = 0; k < 8; ++k) rreg[k] = r4[k*64 + lane];

    // ---- 2. e loads: BOTH 8KB tiles, 16 coalesced 1KB loads in flight ----
    const long t0 = (long)blockIdx.x * 2;     // tiles of 32 rows; 6250 total
    const float4* e4 = (const float4*)emb_e;
    float4 er0[8], er1[8];
#pragma unroll
    for (int k = 0; k < 8; ++k) er0[k] = e4[t0*512 + k*64 + lane];
#pragma unroll
    for (int k = 0; k < 8; ++k) er1[k] = e4[t0*512 + 512 + k*64 + lane];
    asm volatile("" ::: "memory");   // pin load issue order; no sinking

    // ---- 3. q: LDS bounce -> fragments (hi + exact-residual bf16) ----
#pragma unroll
    for (int k = 0; k < 8; ++k) {             // compiler waits vmcnt for q only
        unsigned p = (unsigned)(k*1024 + lane*16);
        float4 sv = sreg[k], rv = rreg[k];
        float4 q = make_float4(sv.x+rv.x, sv.y+rv.y, sv.z+rv.z, sv.w+rv.w);
        *(float4*)(oq + swz(p)) = q;
    }
    lgkm0_fence();

    bf16x8 qh[4], ql[4];
    float qn_part = 0.f;
#pragma unroll
    for (int tt = 0; tt < 4; ++tt) {
        unsigned p0 = (unsigned)(m*256 + h*32 + tt*64);
        float4 q0 = *(const float4*)(oq + swz(p0));
        float4 q1 = *(const float4*)(oq + swz(p0 + 16));
        float qf[8] = {q0.x,q0.y,q0.z,q0.w, q1.x,q1.y,q1.z,q1.w};
#pragma unroll
        for (int i = 0; i < 8; ++i) {
            float f = qf[i];
            qn_part = fmaf(f, f, qn_part);
            unsigned u = __float_as_uint(f);
            qh[tt][i] = (short)(u >> 16);                        // trunc hi
            float lo = f - __uint_as_float(u & 0xFFFF0000u);     // exact resid
            ql[tt][i] = (short)(__float_as_uint(lo) >> 16);
        }
    }
    float qn_own = qn_part + __shfl_xor(qn_part, 32);
    float qn_all[32];
#pragma unroll
    for (int i = 0; i < 32; ++i)
        qn_all[i] = __uint_as_float(
            __builtin_amdgcn_readlane(__float_as_uint(qn_own), i));

    // ---- 4. per-tile: regs -> LDS (frag layout) -> pack -> 8 MFMA ----
    auto do_tile = [&](const float4 (&er)[8], int j) {
        lgkm0_fence();                 // prior frag reads done (WAR on eT/oq)
#pragma unroll
        for (int k = 0; k < 8; ++k) { // compiler emits counted vmcnt here
            unsigned p = (unsigned)(k*1024 + lane*16);
            *(float4*)(eT + swz(p)) = er[k];
        }
        lgkm0_fence();

        f32x16 acc;
#pragma unroll
        for (int i = 0; i < 16; ++i) acc[i] = 0.f;
        float en_part = 0.f;
#pragma unroll
        for (int tt = 0; tt < 4; ++tt) {
            unsigned p0 = (unsigned)(m*256 + h*32 + tt*64);
            float4 e0 = *(const float4*)(eT + swz(p0));
            float4 e1 = *(const float4*)(eT + swz(p0 + 16));
            en_part = fmaf(e0.x, e0.x, en_part);
            en_part = fmaf(e0.y, e0.y, en_part);
            en_part = fmaf(e0.z, e0.z, en_part);
            en_part = fmaf(e0.w, e0.w, en_part);
            en_part = fmaf(e1.x, e1.x, en_part);
            en_part = fmaf(e1.y, e1.y, en_part);
            en_part = fmaf(e1.z, e1.z, en_part);
            en_part = fmaf(e1.w, e1.w, en_part);
            unsigned ep0 = __builtin_amdgcn_perm(__float_as_uint(e0.y),
                                                 __float_as_uint(e0.x), 0x07060302u);
            unsigned ep1 = __builtin_amdgcn_perm(__float_as_uint(e0.w),
                                                 __float_as_uint(e0.z), 0x07060302u);
            unsigned ep2 = __builtin_amdgcn_perm(__float_as_uint(e1.y),
                                                 __float_as_uint(e1.x), 0x07060302u);
            unsigned ep3 = __builtin_amdgcn_perm(__float_as_uint(e1.w),
                                                 __float_as_uint(e1.z), 0x07060302u);
            bf16x8 eh;
            *(unsigned*)&eh       = ep0;
            *((unsigned*)&eh + 1) = ep1;
            *((unsigned*)&eh + 2) = ep2;
            *((unsigned*)&eh + 3) = ep3;
            acc = __builtin_amdgcn_mfma_f32_32x32x16_bf16(qh[tt], eh, acc, 0,0,0);
            acc = __builtin_amdgcn_mfma_f32_32x32x16_bf16(ql[tt], eh, acc, 0,0,0);
        }
        float en = en_part + __shfl_xor(en_part, 32);
        float* outT = (float*)oq;
#pragma unroll
        for (int r = 0; r < 16; ++r) {
            int bb = (r & 3) + 8*(r >> 2);
            int b  = bb + 4*h;
            float d2 = fmaxf(fmaf(-2.f, acc[r], qn_all[b] + en), 0.f);
            outT[b*64 + j*32 + m] = MARGIN - sqrtf(d2);
        }
    };

    do_tile(er0, 0);
    do_tile(er1, 1);
    lgkm0_fence();

    // ---- 5. store: 8 x 1KB instrs, 256B-aligned segments ----
    const float* outT = (const float*)oq;
    const long nb = t0 * 32;                   // 64-row base
#pragma unroll
    for (int k = 0; k < 8; ++k) {
        int rb = 4*k + (lane >> 4);
        int c0 = (lane & 15) * 4;
        float4 v = *(const float4*)(outT + rb*64 + c0);
        *(float4*)(out + (size_t)rb * N + nb + c0) = v;
    }
}

extern "C" void kernel_launch(void* const* d_in, const int* in_sizes, int n_in,
                              void* d_out, int out_size, void* d_ws, size_t ws_size,
                              hipStream_t stream) {
    const float* s = (const float*)d_in[0];
    const float* r = (const float*)d_in[1];
    const float* e = (const float*)d_in[2];
    float* out = (float*)d_out;

    const int N = in_sizes[2] / 64;            // 200000
    const int grid = N / 64;                   // 3125 one-wave blocks

    transe9<<<grid, 64, 0, stream>>>(s, r, e, out, N);
}